// Round 13
// baseline (144.084 us; speedup 1.0000x reference)
//
#include <hip/hip_runtime.h>
#include <math.h>

#define HH 224
#define WW 224
#define BB 8
#define NC 196
#define NBHD 10
#define SS 16
#define MW_OVER_S 0.625f   // M_WEIGHT / S = 10.0 / 16 (exactly representable)

// -------------------------------------------------------------------------
// FUSED _find_minima: window scan + occupancy resolve in ONE kernel.
// 8 blocks (one per batch) x 1024 threads (16 waves).
//  Phase 1 (scan): wave v handles windows c = v, v+16, ... Each window:
//    two-pass (min, then equal-count + min-flat-index) with the exact
//    logic validated in rounds 4-11; results stay in LDS.
//  Phase 2 (resolve): parallel winner fast path when all minima unique
//    (20x20 windows at pitch 16 -> only grid-neighbor windows overlap;
//    bumped <=> an earlier neighbor has equal idx). Fallback: exact
//    sequential occupancy loop with occ bitmap in GLOBAL ws (volatile
//    reads + threadfence for same-CU L1 safety; never taken for
//    continuous random input).
//  Tail: fused init-colors gather + coalesced result writes.
// -------------------------------------------------------------------------
__global__ void k_resolve(const float* __restrict__ g,
                          const float* __restrict__ x,
                          int* __restrict__ yc, int* __restrict__ xc,
                          float* __restrict__ colors,
                          float* __restrict__ out_cents,
                          unsigned char* __restrict__ occ_ws) {
    __shared__ int s_idx[NC];
    __shared__ int s_cnt[NC];
    __shared__ float s_minv[NC];
    __shared__ int s_tie;
    int b = blockIdx.x;
    int t = threadIdx.x;
    int lane = t & 63, wv = t >> 6;          // 16 waves
    const float* gb = g + b * HH * WW;
    const float* xb = x + b * 3 * HH * WW;

    if (t == 0) s_tie = 0;

    // ---- phase 1: window scan (wave-parallel over windows)
    for (int c = wv; c < NC; c += 16) {
        int gy = 8 + 16 * (c / 14), gx = 8 + 16 * (c % 14);
        int y0 = max(0, gy - NBHD), y1 = min(HH, gy + NBHD);
        int x0 = max(0, gx - NBHD), x1 = min(WW, gx + NBHD);
        int wd = x1 - x0;
        int n = (y1 - y0) * wd;

        // pass 1: window min (exact; no fp-order concern)
        float m = INFINITY;
        for (int i = lane; i < n; i += 64) {
            int y = y0 + i / wd, xx = x0 + i % wd;
            m = fminf(m, gb[y * WW + xx]);
        }
        for (int off = 1; off < 64; off <<= 1)
            m = fminf(m, __shfl_xor(m, off));

        // pass 2: equal count + min flat index among equals (L1-hot)
        int bidx = 0x7fffffff;
        int cnt = 0;
        for (int i = lane; i < n; i += 64) {
            int y = y0 + i / wd, xx = x0 + i % wd;
            int f = y * WW + xx;
            if (gb[f] == m) { bidx = min(bidx, f); ++cnt; }
        }
        for (int off = 1; off < 64; off <<= 1) {
            bidx = min(bidx, __shfl_xor(bidx, off));
            cnt += __shfl_xor(cnt, off);
        }
        if (lane == 0) {
            s_minv[c] = m;
            s_idx[c] = bidx;
            s_cnt[c] = cnt;
        }
    }
    __syncthreads();

    // ---- tie detection (benign same-value race on s_tie)
    if (t < NC && s_cnt[t] > 1) s_tie = 1;
    __syncthreads();

    if (!s_tie) {
        // ---- fast path: parallel winner resolve (one thread per centroid)
        if (t < NC) {
            int c = t;
            int idx = s_idx[c];
            int row = c / 14, col = c % 14;
            bool bumped = (col > 0 && s_idx[c - 1] == idx);
            if (row > 0) {
                bumped |= (s_idx[c - 14] == idx);
                if (col > 0)  bumped |= (s_idx[c - 15] == idx);
                if (col < 13) bumped |= (s_idx[c - 13] == idx);
            }
            int ny, nx;
            if (bumped) { ny = 8 + 16 * row; nx = 8 + 16 * col; }   // keep grid centroid
            else        { ny = idx / WW;     nx = idx % WW;     }
            yc[b * NC + c] = ny; xc[b * NC + c] = nx;
            out_cents[(b * NC + c) * 2 + 0] = (float)ny;
            out_cents[(b * NC + c) * 2 + 1] = (float)nx;
            int p = ny * WW + nx;
            colors[(b * NC + c) * 3 + 0] = xb[p];
            colors[(b * NC + c) * 3 + 1] = xb[HH * WW + p];
            colors[(b * NC + c) * 3 + 2] = xb[2 * HH * WW + p];
        }
        return;
    }

    // ---- fallback: exact sequential occupancy resolve (rare: ties exist).
    // occ bitmap in global ws; volatile reads bypass L1 (same-CU RAW safety).
    unsigned char* occ = occ_ws + b * HH * WW;
    volatile unsigned char* occv = occ;
    unsigned int* occ32 = (unsigned int*)occ;
    for (int i = t; i < (HH * WW) / 4; i += 1024) occ32[i] = 0u;
    __threadfence();
    __syncthreads();

    for (int c = 0; c < NC; ++c) {
        int chosen = -2;                      // computed by wave 0 only
        if (t < 64) {
            int idx = s_idx[c];
            int cnt = s_cnt[c];
            bool occd = (occv[idx] != 0);     // uniform broadcast read (L1-bypass)
            if (cnt == 1) {
                chosen = occd ? -1 : idx;
            } else if (!occd) {
                chosen = idx;
            } else {
                // multiple equal minima and the first is occupied -> rescan
                float m = s_minv[c];
                int gy = 8 + 16 * (c / 14), gx = 8 + 16 * (c % 14);
                int wy0 = max(0, gy - NBHD), wy1 = min(HH, gy + NBHD);
                int wx0 = max(0, gx - NBHD), wx1 = min(WW, gx + NBHD);
                int wd = wx1 - wx0;
                int n = (wy1 - wy0) * wd;
                int best = 0x7fffffff;
                for (int i = lane; i < n; i += 64) {
                    int y = wy0 + i / wd, xx = wx0 + i % wd;
                    int f = y * WW + xx;
                    if (gb[f] == m && !occv[f]) best = min(best, f);
                }
                for (int off = 1; off < 64; off <<= 1)
                    best = min(best, __shfl_xor(best, off));
                chosen = (best == 0x7fffffff) ? -1 : best;
            }
            int ny, nx;
            if (chosen >= 0) {
                ny = chosen / WW; nx = chosen % WW;
                if (t == 0) { occ[chosen] = 1; __threadfence(); }
            } else {
                ny = 8 + 16 * (c / 14); nx = 8 + 16 * (c % 14);
            }
            if (t == 0) {
                yc[b * NC + c] = ny;
                xc[b * NC + c] = nx;
                out_cents[(b * NC + c) * 2 + 0] = (float)ny;
                out_cents[(b * NC + c) * 2 + 1] = (float)nx;
            }
        }
        __syncthreads();   // occ + yc/xc writes visible before next iteration
    }
    if (t < NC) {
        int y = yc[b * NC + t], xx = xc[b * NC + t];
        int idx = y * WW + xx;
        colors[(b * NC + t) * 3 + 0] = xb[idx];
        colors[(b * NC + t) * 3 + 1] = xb[HH * WW + idx];
        colors[(b * NC + t) * 3 + 2] = xb[2 * HH * WW + idx];
    }
}

// -------------------------------------------------------------------------
// Assignment: one 16x16 tile per block; candidate list via bbox intersect
// built with wave-ballot compaction (order-independent under the (d,k)
// lexicographic tie-break). _rn arithmetic matches the reference's unfused
// eval. (Validated round 11, absmax 0.0.)
// -------------------------------------------------------------------------
__global__ void k_assign(const float* __restrict__ x,
                         const int* __restrict__ yc,
                         const int* __restrict__ xc,
                         const float* __restrict__ colors,
                         float* __restrict__ lblf) {
    __shared__ int s_yc[NC], s_xc[NC];
    __shared__ float s_c0[NC], s_c1[NC], s_c2[NC], s_cc[NC];
    __shared__ int s_cand[NC];
    __shared__ int s_wc[4];
    int b = blockIdx.z;
    int ty0 = blockIdx.y * 16, tx0 = blockIdx.x * 16;
    int t = threadIdx.y * 16 + threadIdx.x;
    int lane = t & 63, wid = t >> 6;

    bool pred = false;
    if (t < NC) {
        int yck = yc[b * NC + t], xck = xc[b * NC + t];
        s_yc[t] = yck; s_xc[t] = xck;
        float c0 = colors[(b * NC + t) * 3 + 0];
        float c1 = colors[(b * NC + t) * 3 + 1];
        float c2 = colors[(b * NC + t) * 3 + 2];
        s_c0[t] = c0; s_c1[t] = c1; s_c2[t] = c2;
        s_cc[t] = __fadd_rn(__fadd_rn(__fmul_rn(c0, c0), __fmul_rn(c1, c1)), __fmul_rn(c2, c2));
        pred = (yck > ty0 - 17 && yck < ty0 + 32 && xck > tx0 - 17 && xck < tx0 + 32);
    }
    unsigned long long bm = __ballot(pred);
    if (lane == 0) s_wc[wid] = __popcll(bm);
    __syncthreads();
    int base = 0;
    for (int w = 0; w < wid; ++w) base += s_wc[w];
    if (pred) {
        int pos = base + __popcll(bm & ((1ull << lane) - 1ull));
        s_cand[pos] = t;
    }
    int n = s_wc[0] + s_wc[1] + s_wc[2] + s_wc[3];
    __syncthreads();

    int h = ty0 + threadIdx.y, w = tx0 + threadIdx.x;
    const float* xb = x + b * 3 * HH * WW;
    int pidx = h * WW + w;
    float x0v = xb[pidx];
    float x1v = xb[HH * WW + pidx];
    float x2v = xb[2 * HH * WW + pidx];
    float px2 = __fadd_rn(__fadd_rn(__fmul_rn(x0v, x0v), __fmul_rn(x1v, x1v)), __fmul_rn(x2v, x2v));
    float hf = (float)h, wf = (float)w;

    float best = INFINITY;
    int bestk = -1;
    for (int i = 0; i < n; ++i) {
        int k = s_cand[i];
        int yck = s_yc[k], xck = s_xc[k];
        if (h >= yck - SS && h < yck + SS && w >= xck - SS && w < xck + SS) {
            float cross = __fadd_rn(__fadd_rn(__fmul_rn(x0v, s_c0[k]), __fmul_rn(x1v, s_c1[k])),
                                    __fmul_rn(x2v, s_c2[k]));
            float t2 = __fsub_rn(__fadd_rn(px2, s_cc[k]), __fmul_rn(2.0f, cross));
            float cd = __fsqrt_rn(fmaxf(t2, 0.0f));
            float dy = __fsub_rn(hf, (float)yck);
            float dx = __fsub_rn(wf, (float)xck);
            float sp = __fsqrt_rn(__fadd_rn(__fmul_rn(dy, dy), __fmul_rn(dx, dx)));
            float d = __fadd_rn(cd, __fmul_rn(MW_OVER_S, sp));
            if (d < best || (d == best && k < bestk)) { best = d; bestk = k; }
        }
    }
    lblf[b * HH * WW + pidx] = (float)bestk;
}

// -------------------------------------------------------------------------
// Update step: one 256-thread block per (b, k). Order-preserving compaction
// into LDS, then pipelined ordered serial channel sums (same left-fold add
// SEQUENCE as the reference's segment_sum; loads batched as ds_read_b128).
// (Validated round 11, absmax 0.0.)
// -------------------------------------------------------------------------
__global__ void k_update(const float* __restrict__ x,
                         const float* __restrict__ lblf,
                         int* __restrict__ yc, int* __restrict__ xc,
                         float* __restrict__ colors) {
    __shared__ alignas(16) float sc0[1024];
    __shared__ alignas(16) float sc1[1024];
    __shared__ alignas(16) float sc2[1024];
    __shared__ int wsum[4];
    __shared__ int s_isy, s_isx;
    __shared__ float s_fin[3];
    int k = blockIdx.x, b = blockIdx.y;
    int t = threadIdx.x;
    int lane = t & 63, wid = t >> 6;

    int yck = yc[b * NC + k], xck = xc[b * NC + k];
    int y0 = max(0, yck - SS), y1 = min(HH, yck + SS);
    int x0 = max(0, xck - SS), x1 = min(WW, xck + SS);
    int wd = x1 - x0;
    int n = (y1 - y0) * wd;          // <= 1024 = 4 * 256 threads

    const float* xb = x + b * 3 * HH * WW;
    const float* lb = lblf + b * HH * WW;
    float kf = (float)k;

    if (t == 0) { s_isy = 0; s_isx = 0; }
    __syncthreads();

    // pass 1: match mask over this thread's 4 consecutive window-flat indices
    int mask = 0;
    int isy = 0, isx = 0;
    #pragma unroll
    for (int j = 0; j < 4; ++j) {
        int i = 4 * t + j;
        if (i < n) {
            int y = y0 + i / wd, xx = x0 + i % wd;
            if (lb[y * WW + xx] == kf) { mask |= (1 << j); isy += y; isx += xx; }
        }
    }
    int c_t = __popc(mask);

    // wave inclusive scan of per-thread counts
    int inc = c_t;
    for (int off = 1; off < 64; off <<= 1) {
        int u = __shfl_up(inc, off);
        if (lane >= off) inc += u;
    }
    if (lane == 63) wsum[wid] = inc;
    __syncthreads();
    int woff = 0;
    for (int w = 0; w < wid; ++w) woff += wsum[w];
    int pos = woff + inc - c_t;      // exclusive prefix = this thread's write base

    // pass 2: order-preserving compaction of matched colors into LDS
    #pragma unroll
    for (int j = 0; j < 4; ++j) {
        if ((mask >> j) & 1) {
            int i = 4 * t + j;
            int y = y0 + i / wd, xx = x0 + i % wd;
            int idx = y * WW + xx;
            sc0[pos] = xb[idx];
            sc1[pos] = xb[HH * WW + idx];
            sc2[pos] = xb[2 * HH * WW + idx];
            ++pos;
        }
    }
    // integer reductions (exact in any order)
    for (int off = 1; off < 64; off <<= 1) {
        isy += __shfl_xor(isy, off);
        isx += __shfl_xor(isx, off);
    }
    if (lane == 0) { atomicAdd(&s_isy, isy); atomicAdd(&s_isx, isx); }
    __syncthreads();

    int cnt = wsum[0] + wsum[1] + wsum[2] + wsum[3];

    // ordered serial channel sums, pipelined: lanes 0/1/2, one channel each
    if (t < 3) {
        const float* a = (t == 0) ? sc0 : (t == 1) ? sc1 : sc2;
        float s = 0.0f;
        int i = 0;
        for (; i + 8 <= cnt; i += 8) {
            float4 q0 = *(const float4*)(a + i);      // ds_read_b128
            float4 q1 = *(const float4*)(a + i + 4);  // ds_read_b128
            s = __fadd_rn(s, q0.x); s = __fadd_rn(s, q0.y);
            s = __fadd_rn(s, q0.z); s = __fadd_rn(s, q0.w);
            s = __fadd_rn(s, q1.x); s = __fadd_rn(s, q1.y);
            s = __fadd_rn(s, q1.z); s = __fadd_rn(s, q1.w);
        }
        for (; i < cnt; ++i) s = __fadd_rn(s, a[i]);
        s_fin[t] = s;
    }
    __syncthreads();

    if (t == 0 && cnt > 0) {
        float denom = (float)cnt;
        // reference: round(clip(sum/denom, 0, 223)); jnp.round == rint
        float nyf = rintf(fminf(fmaxf(__fdiv_rn((float)s_isy, denom), 0.0f), (float)(HH - 1)));
        float nxf = rintf(fminf(fmaxf(__fdiv_rn((float)s_isx, denom), 0.0f), (float)(WW - 1)));
        yc[b * NC + k] = (int)nyf;
        xc[b * NC + k] = (int)nxf;
        colors[(b * NC + k) * 3 + 0] = __fdiv_rn(s_fin[0], denom);
        colors[(b * NC + k) * 3 + 1] = __fdiv_rn(s_fin[1], denom);
        colors[(b * NC + k) * 3 + 2] = __fdiv_rn(s_fin[2], denom);
    }
}

// -------------------------------------------------------------------------
// Launch sequence (4 dispatches):
//   resolve(scan+resolve+init_colors) -> assign -> update -> assign
// (MAX_ITER=2: only lbl escapes the reference loop, so the 2nd iteration's
//  update is dead and elided.)
// -------------------------------------------------------------------------
extern "C" void kernel_launch(void* const* d_in, const int* in_sizes, int n_in,
                              void* d_out, int out_size, void* d_ws, size_t ws_size,
                              hipStream_t stream) {
    const float* x = (const float*)d_in[0];      // (8,3,224,224) f32
    const float* g = (const float*)d_in[1];      // (8,1,224,224) f32
    float* out = (float*)d_out;
    float* out_cents = out;                      // 8*196*2 floats
    float* lblf = out + BB * NC * 2;             // 8*224*224 floats (labels as f32)

    // workspace layout
    int* yc = (int*)d_ws;                        // BB*NC
    int* xc = yc + BB * NC;                      // BB*NC
    float* colors = (float*)(xc + BB * NC);      // BB*NC*3
    unsigned char* occ_ws = (unsigned char*)(colors + BB * NC * 3);  // BB*HH*WW (fallback only)

    k_resolve<<<BB, 1024, 0, stream>>>(g, x, yc, xc, colors, out_cents, occ_ws);

    dim3 gridA(WW / 16, HH / 16, BB);
    dim3 blkA(16, 16);
    dim3 gupd(NC, BB);
    k_assign<<<gridA, blkA, 0, stream>>>(x, yc, xc, colors, lblf);   // iter 0 assign
    k_update<<<gupd, 256, 0, stream>>>(x, lblf, yc, xc, colors);     // iter 0 update
    k_assign<<<gridA, blkA, 0, stream>>>(x, yc, xc, colors, lblf);   // iter 1 assign (final)
}

// Round 14
// 94.223 us; speedup vs baseline: 1.5292x; 1.5292x over previous
//
#include <hip/hip_runtime.h>
#include <math.h>

#define HH 224
#define WW 224
#define BB 8
#define NC 196
#define NBHD 10
#define SS 16
#define MW_OVER_S 0.625f   // M_WEIGHT / S = 10.0 / 16 (exactly representable)

// -------------------------------------------------------------------------
// Phase A of _find_minima: per (batch, centroid) window min / min-flat-index
// among equals / equal count. Fully parallel: grid (NC, BB), 1 wave.
// NOTE (round-13 lesson): keeping this as its own 1568-block dispatch is
// ESSENTIAL — fusing it into the 8-block resolve kernel collapsed the
// latency-hiding parallelism and regressed 93.6 -> 144 us.
// (Validated rounds 4-11.)
// -------------------------------------------------------------------------
__global__ void k_window_scan(const float* __restrict__ g,
                              float* __restrict__ wmin,
                              int* __restrict__ widx,
                              int* __restrict__ wcnt) {
    int c = blockIdx.x, b = blockIdx.y;
    int lane = threadIdx.x;
    const float* gb = g + b * HH * WW;
    int gy = 8 + 16 * (c / 14), gx = 8 + 16 * (c % 14);
    int y0 = max(0, gy - NBHD), y1 = min(HH, gy + NBHD);
    int x0 = max(0, gx - NBHD), x1 = min(WW, gx + NBHD);
    int wd = x1 - x0;
    int n = (y1 - y0) * wd;

    // pass 1: window min (min-reduce is exact; no fp-ordering concern)
    float m = INFINITY;
    for (int i = lane; i < n; i += 64) {
        int y = y0 + i / wd, x = x0 + i % wd;
        m = fminf(m, gb[y * WW + x]);
    }
    for (int off = 1; off < 64; off <<= 1)
        m = fminf(m, __shfl_xor(m, off));

    // pass 2: count equals + min flat index among equals (L1/L2-hot)
    int bidx = 0x7fffffff;
    int cnt = 0;
    for (int i = lane; i < n; i += 64) {
        int y = y0 + i / wd, x = x0 + i % wd;
        int f = y * WW + x;
        if (gb[f] == m) { bidx = min(bidx, f); ++cnt; }
    }
    for (int off = 1; off < 64; off <<= 1) {
        bidx = min(bidx, __shfl_xor(bidx, off));
        cnt += __shfl_xor(cnt, off);
    }
    if (lane == 0) {
        wmin[b * NC + c] = m;
        widx[b * NC + c] = bidx;
        wcnt[b * NC + c] = cnt;
    }
}

// -------------------------------------------------------------------------
// Phase B of _find_minima: parallel winner resolve when all window minima
// are unique (20x20 windows at pitch 16 -> only grid-neighbor windows
// overlap; "bumped" <=> an earlier neighbor has equal idx). Fallback to the
// exact sequential occupancy loop if any tie exists (never taken for
// continuous random input). Validated rounds 9/11 (absmax 0.0).
// Tail: fused init-colors gather + coalesced result writes.
// -------------------------------------------------------------------------
__global__ void k_resolve(const float* __restrict__ g,
                          const float* __restrict__ x,
                          const float* __restrict__ wmin,
                          const int* __restrict__ widx,
                          const int* __restrict__ wcnt,
                          int* __restrict__ yc, int* __restrict__ xc,
                          float* __restrict__ colors,
                          float* __restrict__ out_cents) {
    __shared__ int s_idx[NC];
    __shared__ int s_cnt[NC];
    __shared__ float s_minv[NC];
    __shared__ unsigned char occ[HH * WW];   // fallback path only
    int b = blockIdx.x, lane = threadIdx.x;
    const float* gb = g + b * HH * WW;
    const float* xb = x + b * 3 * HH * WW;

    for (int i = lane; i < NC; i += 64) {
        s_idx[i] = widx[b * NC + i];
        s_cnt[i] = wcnt[b * NC + i];
        s_minv[i] = wmin[b * NC + i];
    }
    __syncthreads();

    bool tie = false;
    for (int i = lane; i < NC; i += 64) tie |= (s_cnt[i] > 1);
    if (!__any(tie)) {
        // ---- fast path: parallel winner resolve (all window minima unique)
        for (int c = lane; c < NC; c += 64) {
            int idx = s_idx[c];
            int row = c / 14, col = c % 14;
            bool bumped = (col > 0 && s_idx[c - 1] == idx);
            if (row > 0) {
                bumped |= (s_idx[c - 14] == idx);
                if (col > 0)  bumped |= (s_idx[c - 15] == idx);
                if (col < 13) bumped |= (s_idx[c - 13] == idx);
            }
            int ny, nx;
            if (bumped) { ny = 8 + 16 * row; nx = 8 + 16 * col; }   // keep grid centroid
            else        { ny = idx / WW;     nx = idx % WW;     }
            yc[b * NC + c] = ny; xc[b * NC + c] = nx;
            out_cents[(b * NC + c) * 2 + 0] = (float)ny;
            out_cents[(b * NC + c) * 2 + 1] = (float)nx;
            int p = ny * WW + nx;
            colors[(b * NC + c) * 3 + 0] = xb[p];
            colors[(b * NC + c) * 3 + 1] = xb[HH * WW + p];
            colors[(b * NC + c) * 3 + 2] = xb[2 * HH * WW + p];
        }
        return;
    }

    // ---- fallback: exact sequential occupancy resolve (rare: ties exist)
    unsigned int* occ32 = (unsigned int*)occ;
    for (int i = lane; i < (HH * WW) / 4; i += 64) occ32[i] = 0u;
    __syncthreads();

    for (int c = 0; c < NC; ++c) {
        int idx = s_idx[c];
        int cnt = s_cnt[c];
        bool occd = (occ[idx] != 0);      // wave-uniform broadcast read
        int chosen;
        if (cnt == 1) {
            chosen = occd ? -1 : idx;
        } else if (!occd) {
            chosen = idx;
        } else {
            // multiple equal minima and the first is occupied -> rescan
            float m = s_minv[c];
            int gy = 8 + 16 * (c / 14), gx = 8 + 16 * (c % 14);
            int wy0 = max(0, gy - NBHD), wy1 = min(HH, gy + NBHD);
            int wx0 = max(0, gx - NBHD), wx1 = min(WW, gx + NBHD);
            int wd = wx1 - wx0;
            int n = (wy1 - wy0) * wd;
            int best = 0x7fffffff;
            for (int i = lane; i < n; i += 64) {
                int y = wy0 + i / wd, xx = wx0 + i % wd;
                int f = y * WW + xx;
                if (gb[f] == m && !occ[f]) best = min(best, f);
            }
            for (int off = 1; off < 64; off <<= 1)
                best = min(best, __shfl_xor(best, off));
            chosen = (best == 0x7fffffff) ? -1 : best;
        }
        int ny, nx;
        if (chosen >= 0) {
            ny = chosen / WW; nx = chosen % WW;
            if (lane == 0) occ[chosen] = 1;
        } else {
            ny = 8 + 16 * (c / 14); nx = 8 + 16 * (c % 14);
        }
        if (lane == 0) {
            yc[b * NC + c] = ny;
            xc[b * NC + c] = nx;
            out_cents[(b * NC + c) * 2 + 0] = (float)ny;
            out_cents[(b * NC + c) * 2 + 1] = (float)nx;
        }
        __syncthreads();
    }
    for (int k = lane; k < NC; k += 64) {
        int y = yc[b * NC + k], xx = xc[b * NC + k];
        int idx = y * WW + xx;
        colors[(b * NC + k) * 3 + 0] = xb[idx];
        colors[(b * NC + k) * 3 + 1] = xb[HH * WW + idx];
        colors[(b * NC + k) * 3 + 2] = xb[2 * HH * WW + idx];
    }
}

// -------------------------------------------------------------------------
// Assignment: one 16x16 tile per block; candidate list via bbox intersect
// built with wave-ballot compaction (order-independent under the (d,k)
// lexicographic tie-break). _rn arithmetic matches the reference's unfused
// eval. (Validated round 11, absmax 0.0.)
// -------------------------------------------------------------------------
__global__ void k_assign(const float* __restrict__ x,
                         const int* __restrict__ yc,
                         const int* __restrict__ xc,
                         const float* __restrict__ colors,
                         float* __restrict__ lblf) {
    __shared__ int s_yc[NC], s_xc[NC];
    __shared__ float s_c0[NC], s_c1[NC], s_c2[NC], s_cc[NC];
    __shared__ int s_cand[NC];
    __shared__ int s_wc[4];
    int b = blockIdx.z;
    int ty0 = blockIdx.y * 16, tx0 = blockIdx.x * 16;
    int t = threadIdx.y * 16 + threadIdx.x;
    int lane = t & 63, wid = t >> 6;

    bool pred = false;
    if (t < NC) {
        int yck = yc[b * NC + t], xck = xc[b * NC + t];
        s_yc[t] = yck; s_xc[t] = xck;
        float c0 = colors[(b * NC + t) * 3 + 0];
        float c1 = colors[(b * NC + t) * 3 + 1];
        float c2 = colors[(b * NC + t) * 3 + 2];
        s_c0[t] = c0; s_c1[t] = c1; s_c2[t] = c2;
        s_cc[t] = __fadd_rn(__fadd_rn(__fmul_rn(c0, c0), __fmul_rn(c1, c1)), __fmul_rn(c2, c2));
        pred = (yck > ty0 - 17 && yck < ty0 + 32 && xck > tx0 - 17 && xck < tx0 + 32);
    }
    unsigned long long bm = __ballot(pred);
    if (lane == 0) s_wc[wid] = __popcll(bm);
    __syncthreads();
    int base = 0;
    for (int w = 0; w < wid; ++w) base += s_wc[w];
    if (pred) {
        int pos = base + __popcll(bm & ((1ull << lane) - 1ull));
        s_cand[pos] = t;
    }
    int n = s_wc[0] + s_wc[1] + s_wc[2] + s_wc[3];
    __syncthreads();

    int h = ty0 + threadIdx.y, w = tx0 + threadIdx.x;
    const float* xb = x + b * 3 * HH * WW;
    int pidx = h * WW + w;
    float x0v = xb[pidx];
    float x1v = xb[HH * WW + pidx];
    float x2v = xb[2 * HH * WW + pidx];
    float px2 = __fadd_rn(__fadd_rn(__fmul_rn(x0v, x0v), __fmul_rn(x1v, x1v)), __fmul_rn(x2v, x2v));
    float hf = (float)h, wf = (float)w;

    float best = INFINITY;
    int bestk = -1;
    for (int i = 0; i < n; ++i) {
        int k = s_cand[i];
        int yck = s_yc[k], xck = s_xc[k];
        if (h >= yck - SS && h < yck + SS && w >= xck - SS && w < xck + SS) {
            float cross = __fadd_rn(__fadd_rn(__fmul_rn(x0v, s_c0[k]), __fmul_rn(x1v, s_c1[k])),
                                    __fmul_rn(x2v, s_c2[k]));
            float t2 = __fsub_rn(__fadd_rn(px2, s_cc[k]), __fmul_rn(2.0f, cross));
            float cd = __fsqrt_rn(fmaxf(t2, 0.0f));
            float dy = __fsub_rn(hf, (float)yck);
            float dx = __fsub_rn(wf, (float)xck);
            float sp = __fsqrt_rn(__fadd_rn(__fmul_rn(dy, dy), __fmul_rn(dx, dx)));
            float d = __fadd_rn(cd, __fmul_rn(MW_OVER_S, sp));
            if (d < best || (d == best && k < bestk)) { best = d; bestk = k; }
        }
    }
    lblf[b * HH * WW + pidx] = (float)bestk;
}

// -------------------------------------------------------------------------
// Update step: one 256-thread block per (b, k). Order-preserving compaction
// into LDS, then pipelined ordered serial channel sums (same left-fold add
// SEQUENCE as the reference's segment_sum; loads batched as ds_read_b128).
// (Validated round 11, absmax 0.0.)
// -------------------------------------------------------------------------
__global__ void k_update(const float* __restrict__ x,
                         const float* __restrict__ lblf,
                         int* __restrict__ yc, int* __restrict__ xc,
                         float* __restrict__ colors) {
    __shared__ alignas(16) float sc0[1024];
    __shared__ alignas(16) float sc1[1024];
    __shared__ alignas(16) float sc2[1024];
    __shared__ int wsum[4];
    __shared__ int s_isy, s_isx;
    __shared__ float s_fin[3];
    int k = blockIdx.x, b = blockIdx.y;
    int t = threadIdx.x;
    int lane = t & 63, wid = t >> 6;

    int yck = yc[b * NC + k], xck = xc[b * NC + k];
    int y0 = max(0, yck - SS), y1 = min(HH, yck + SS);
    int x0 = max(0, xck - SS), x1 = min(WW, xck + SS);
    int wd = x1 - x0;
    int n = (y1 - y0) * wd;          // <= 1024 = 4 * 256 threads

    const float* xb = x + b * 3 * HH * WW;
    const float* lb = lblf + b * HH * WW;
    float kf = (float)k;

    if (t == 0) { s_isy = 0; s_isx = 0; }
    __syncthreads();

    // pass 1: match mask over this thread's 4 consecutive window-flat indices
    int mask = 0;
    int isy = 0, isx = 0;
    #pragma unroll
    for (int j = 0; j < 4; ++j) {
        int i = 4 * t + j;
        if (i < n) {
            int y = y0 + i / wd, xx = x0 + i % wd;
            if (lb[y * WW + xx] == kf) { mask |= (1 << j); isy += y; isx += xx; }
        }
    }
    int c_t = __popc(mask);

    // wave inclusive scan of per-thread counts
    int inc = c_t;
    for (int off = 1; off < 64; off <<= 1) {
        int u = __shfl_up(inc, off);
        if (lane >= off) inc += u;
    }
    if (lane == 63) wsum[wid] = inc;
    __syncthreads();
    int woff = 0;
    for (int w = 0; w < wid; ++w) woff += wsum[w];
    int pos = woff + inc - c_t;      // exclusive prefix = this thread's write base

    // pass 2: order-preserving compaction of matched colors into LDS
    #pragma unroll
    for (int j = 0; j < 4; ++j) {
        if ((mask >> j) & 1) {
            int i = 4 * t + j;
            int y = y0 + i / wd, xx = x0 + i % wd;
            int idx = y * WW + xx;
            sc0[pos] = xb[idx];
            sc1[pos] = xb[HH * WW + idx];
            sc2[pos] = xb[2 * HH * WW + idx];
            ++pos;
        }
    }
    // integer reductions (exact in any order)
    for (int off = 1; off < 64; off <<= 1) {
        isy += __shfl_xor(isy, off);
        isx += __shfl_xor(isx, off);
    }
    if (lane == 0) { atomicAdd(&s_isy, isy); atomicAdd(&s_isx, isx); }
    __syncthreads();

    int cnt = wsum[0] + wsum[1] + wsum[2] + wsum[3];

    // ordered serial channel sums, pipelined: lanes 0/1/2, one channel each
    if (t < 3) {
        const float* a = (t == 0) ? sc0 : (t == 1) ? sc1 : sc2;
        float s = 0.0f;
        int i = 0;
        for (; i + 8 <= cnt; i += 8) {
            float4 q0 = *(const float4*)(a + i);      // ds_read_b128
            float4 q1 = *(const float4*)(a + i + 4);  // ds_read_b128
            s = __fadd_rn(s, q0.x); s = __fadd_rn(s, q0.y);
            s = __fadd_rn(s, q0.z); s = __fadd_rn(s, q0.w);
            s = __fadd_rn(s, q1.x); s = __fadd_rn(s, q1.y);
            s = __fadd_rn(s, q1.z); s = __fadd_rn(s, q1.w);
        }
        for (; i < cnt; ++i) s = __fadd_rn(s, a[i]);
        s_fin[t] = s;
    }
    __syncthreads();

    if (t == 0 && cnt > 0) {
        float denom = (float)cnt;
        // reference: round(clip(sum/denom, 0, 223)); jnp.round == rint
        float nyf = rintf(fminf(fmaxf(__fdiv_rn((float)s_isy, denom), 0.0f), (float)(HH - 1)));
        float nxf = rintf(fminf(fmaxf(__fdiv_rn((float)s_isx, denom), 0.0f), (float)(WW - 1)));
        yc[b * NC + k] = (int)nyf;
        xc[b * NC + k] = (int)nxf;
        colors[(b * NC + k) * 3 + 0] = __fdiv_rn(s_fin[0], denom);
        colors[(b * NC + k) * 3 + 1] = __fdiv_rn(s_fin[1], denom);
        colors[(b * NC + k) * 3 + 2] = __fdiv_rn(s_fin[2], denom);
    }
}

// -------------------------------------------------------------------------
// Launch sequence (5 dispatches):
//   window_scan -> resolve(+init_colors) -> assign -> update -> assign
// (MAX_ITER=2: only lbl escapes the reference loop, so the 2nd iteration's
//  update is dead and elided.)
// -------------------------------------------------------------------------
extern "C" void kernel_launch(void* const* d_in, const int* in_sizes, int n_in,
                              void* d_out, int out_size, void* d_ws, size_t ws_size,
                              hipStream_t stream) {
    const float* x = (const float*)d_in[0];      // (8,3,224,224) f32
    const float* g = (const float*)d_in[1];      // (8,1,224,224) f32
    float* out = (float*)d_out;
    float* out_cents = out;                      // 8*196*2 floats
    float* lblf = out + BB * NC * 2;             // 8*224*224 floats (labels as f32)

    // workspace layout (all < 64 KB total)
    int* yc = (int*)d_ws;                        // BB*NC
    int* xc = yc + BB * NC;                      // BB*NC
    float* colors = (float*)(xc + BB * NC);      // BB*NC*3
    float* wmin = colors + BB * NC * 3;          // BB*NC
    int* widx = (int*)(wmin + BB * NC);          // BB*NC
    int* wcnt = widx + BB * NC;                  // BB*NC

    dim3 gscan(NC, BB);
    k_window_scan<<<gscan, 64, 0, stream>>>(g, wmin, widx, wcnt);
    k_resolve<<<BB, 64, 0, stream>>>(g, x, wmin, widx, wcnt, yc, xc, colors, out_cents);

    dim3 gridA(WW / 16, HH / 16, BB);
    dim3 blkA(16, 16);
    dim3 gupd(NC, BB);
    k_assign<<<gridA, blkA, 0, stream>>>(x, yc, xc, colors, lblf);   // iter 0 assign
    k_update<<<gupd, 256, 0, stream>>>(x, lblf, yc, xc, colors);     // iter 0 update
    k_assign<<<gridA, blkA, 0, stream>>>(x, yc, xc, colors, lblf);   // iter 1 assign (final)
}

// Round 15
// 92.516 us; speedup vs baseline: 1.5574x; 1.0185x over previous
//
#include <hip/hip_runtime.h>
#include <math.h>

#define HH 224
#define WW 224
#define BB 8
#define NC 196
#define NBHD 10
#define SS 16
#define MW_OVER_S 0.625f   // M_WEIGHT / S = 10.0 / 16 (exactly representable)

// -------------------------------------------------------------------------
// Phase A of _find_minima: per (batch, centroid) window min / min-flat-index
// among equals / equal count. Fully parallel: grid (NC, BB), 1 wave.
// NOTE (round-13 lesson): keep this as its own 1568-block dispatch —
// fusing it into an 8-block kernel collapsed latency-hiding parallelism
// and regressed 93.6 -> 144 us. (Validated rounds 4-14.)
// -------------------------------------------------------------------------
__global__ void k_window_scan(const float* __restrict__ g,
                              float* __restrict__ wmin,
                              int* __restrict__ widx,
                              int* __restrict__ wcnt) {
    int c = blockIdx.x, b = blockIdx.y;
    int lane = threadIdx.x;
    const float* gb = g + b * HH * WW;
    int gy = 8 + 16 * (c / 14), gx = 8 + 16 * (c % 14);
    int y0 = max(0, gy - NBHD), y1 = min(HH, gy + NBHD);
    int x0 = max(0, gx - NBHD), x1 = min(WW, gx + NBHD);
    int wd = x1 - x0;
    int n = (y1 - y0) * wd;

    // pass 1: window min (min-reduce is exact; no fp-ordering concern)
    float m = INFINITY;
    for (int i = lane; i < n; i += 64) {
        int y = y0 + i / wd, x = x0 + i % wd;
        m = fminf(m, gb[y * WW + x]);
    }
    for (int off = 1; off < 64; off <<= 1)
        m = fminf(m, __shfl_xor(m, off));

    // pass 2: count equals + min flat index among equals (L1/L2-hot)
    int bidx = 0x7fffffff;
    int cnt = 0;
    for (int i = lane; i < n; i += 64) {
        int y = y0 + i / wd, x = x0 + i % wd;
        int f = y * WW + x;
        if (gb[f] == m) { bidx = min(bidx, f); ++cnt; }
    }
    for (int off = 1; off < 64; off <<= 1) {
        bidx = min(bidx, __shfl_xor(bidx, off));
        cnt += __shfl_xor(cnt, off);
    }
    if (lane == 0) {
        wmin[b * NC + c] = m;
        widx[b * NC + c] = bidx;
        wcnt[b * NC + c] = cnt;
    }
}

// -------------------------------------------------------------------------
// Assign (iteration 0) WITH FUSED RESOLVE PROLOGUE.
// Every block redundantly computes the resolve for its batch in LDS
// (~200 L2-hot loads + trivial ALU — hidden under 1568-block parallelism,
// unlike the old 8-block resolve dispatch which was latency-bound at ~8us).
// Fast path: parallel winner formula (validated rounds 9-14: 20x20 windows
// at pitch 16 -> only grid-neighbor windows overlap; bumped <=> an earlier
// neighbor has equal idx). Fallback (ties exist; never taken for continuous
// input): exact sequential occupancy loop with a BIT bitmap (6.3KB LDS so
// the fast path's occupancy is not capped).
// One designated block per batch writes yc/xc/colors/out_cents to ws for
// k_update / assign-2 (stream-ordered).
// Candidate build via wave-ballot compaction; per-pixel argmin with _rn
// arithmetic; lexicographic (d,k) tie-break. (Assign body validated r11.)
// -------------------------------------------------------------------------
__global__ void k_assign_first(const float* __restrict__ g,
                               const float* __restrict__ x,
                               const int* __restrict__ widx,
                               const int* __restrict__ wcnt,
                               const float* __restrict__ wmin,
                               int* __restrict__ yc, int* __restrict__ xc,
                               float* __restrict__ colors,
                               float* __restrict__ out_cents,
                               float* __restrict__ lblf) {
    __shared__ int s_idx[NC], s_cnt[NC];
    __shared__ float s_minv[NC];
    __shared__ int s_yc[NC], s_xc[NC];
    __shared__ float s_c0[NC], s_c1[NC], s_c2[NC], s_cc[NC];
    __shared__ int s_cand[NC];
    __shared__ int s_wc[4];
    __shared__ int s_tie;
    __shared__ int s_bmin[4];
    __shared__ unsigned int occbits[(HH * WW + 31) / 32];   // fallback only (6.3KB)
    int b = blockIdx.z;
    int ty0 = blockIdx.y * 16, tx0 = blockIdx.x * 16;
    int t = threadIdx.y * 16 + threadIdx.x;
    int lane = t & 63, wid = t >> 6;
    const float* gb = g + b * HH * WW;
    const float* xb = x + b * 3 * HH * WW;

    if (t == 0) s_tie = 0;
    if (t < NC) {
        s_idx[t] = widx[b * NC + t];
        s_cnt[t] = wcnt[b * NC + t];
        s_minv[t] = wmin[b * NC + t];
    }
    __syncthreads();
    if (t < NC && s_cnt[t] > 1) s_tie = 1;
    __syncthreads();

    if (!s_tie) {
        // ---- fast path: parallel winner resolve (all window minima unique)
        if (t < NC) {
            int idx = s_idx[t];
            int row = t / 14, col = t % 14;
            bool bumped = (col > 0 && s_idx[t - 1] == idx);
            if (row > 0) {
                bumped |= (s_idx[t - 14] == idx);
                if (col > 0)  bumped |= (s_idx[t - 15] == idx);
                if (col < 13) bumped |= (s_idx[t - 13] == idx);
            }
            int ny, nx;
            if (bumped) { ny = 8 + 16 * row; nx = 8 + 16 * col; }   // keep grid centroid
            else        { ny = idx / WW;     nx = idx % WW;     }
            s_yc[t] = ny; s_xc[t] = nx;
        }
    } else {
        // ---- fallback: exact sequential occupancy resolve (rare; bit bitmap)
        for (int i = t; i < (HH * WW + 31) / 32; i += 256) occbits[i] = 0u;
        __syncthreads();
        for (int c = 0; c < NC; ++c) {
            int idx = s_idx[c];
            int cnt = s_cnt[c];
            bool occd = (occbits[idx >> 5] >> (idx & 31)) & 1;   // uniform read
            int chosen;
            if (cnt == 1) {
                chosen = occd ? -1 : idx;
            } else if (!occd) {
                chosen = idx;
            } else {
                // multiple equal minima and the first is occupied -> rescan
                float m = s_minv[c];
                int gy = 8 + 16 * (c / 14), gx = 8 + 16 * (c % 14);
                int wy0 = max(0, gy - NBHD), wy1 = min(HH, gy + NBHD);
                int wx0 = max(0, gx - NBHD), wx1 = min(WW, gx + NBHD);
                int wdw = wx1 - wx0;
                int nn = (wy1 - wy0) * wdw;
                int best = 0x7fffffff;
                for (int i = t; i < nn; i += 256) {
                    int y = wy0 + i / wdw, xx2 = wx0 + i % wdw;
                    int f = y * WW + xx2;
                    bool o = (occbits[f >> 5] >> (f & 31)) & 1;
                    if (gb[f] == m && !o) best = min(best, f);
                }
                for (int off = 1; off < 64; off <<= 1)
                    best = min(best, __shfl_xor(best, off));
                if (lane == 0) s_bmin[wid] = best;
                __syncthreads();
                best = min(min(s_bmin[0], s_bmin[1]), min(s_bmin[2], s_bmin[3]));
                chosen = (best == 0x7fffffff) ? -1 : best;
            }
            if (t == 0) {
                int ny, nx;
                if (chosen >= 0) {
                    ny = chosen / WW; nx = chosen % WW;
                    occbits[chosen >> 5] |= (1u << (chosen & 31));
                } else {
                    ny = 8 + 16 * (c / 14); nx = 8 + 16 * (c % 14);
                }
                s_yc[c] = ny; s_xc[c] = nx;
            }
            __syncthreads();   // occbits + s_yc/s_xc visible before next iter
        }
    }
    __syncthreads();

    // ---- init-colors gather (same values the old resolve wrote to ws)
    if (t < NC) {
        int p = s_yc[t] * WW + s_xc[t];
        float c0 = xb[p];
        float c1 = xb[HH * WW + p];
        float c2 = xb[2 * HH * WW + p];
        s_c0[t] = c0; s_c1[t] = c1; s_c2[t] = c2;
        s_cc[t] = __fadd_rn(__fadd_rn(__fmul_rn(c0, c0), __fmul_rn(c1, c1)), __fmul_rn(c2, c2));
        // designated block publishes the iter-0 state for k_update / assign-2
        if (blockIdx.x == 0 && blockIdx.y == 0) {
            yc[b * NC + t] = s_yc[t];
            xc[b * NC + t] = s_xc[t];
            out_cents[(b * NC + t) * 2 + 0] = (float)s_yc[t];
            out_cents[(b * NC + t) * 2 + 1] = (float)s_xc[t];
            colors[(b * NC + t) * 3 + 0] = c0;
            colors[(b * NC + t) * 3 + 1] = c1;
            colors[(b * NC + t) * 3 + 2] = c2;
        }
    }

    // ---- candidate build (wave-ballot compaction)
    bool pred = false;
    if (t < NC) {
        int yck = s_yc[t], xck = s_xc[t];
        pred = (yck > ty0 - 17 && yck < ty0 + 32 && xck > tx0 - 17 && xck < tx0 + 32);
    }
    unsigned long long bm = __ballot(pred);
    if (lane == 0) s_wc[wid] = __popcll(bm);
    __syncthreads();
    int base = 0;
    for (int w = 0; w < wid; ++w) base += s_wc[w];
    if (pred) {
        int pos = base + __popcll(bm & ((1ull << lane) - 1ull));
        s_cand[pos] = t;
    }
    int n = s_wc[0] + s_wc[1] + s_wc[2] + s_wc[3];
    __syncthreads();

    // ---- per-pixel argmin
    int h = ty0 + threadIdx.y, w = tx0 + threadIdx.x;
    int pidx = h * WW + w;
    float x0v = xb[pidx];
    float x1v = xb[HH * WW + pidx];
    float x2v = xb[2 * HH * WW + pidx];
    float px2 = __fadd_rn(__fadd_rn(__fmul_rn(x0v, x0v), __fmul_rn(x1v, x1v)), __fmul_rn(x2v, x2v));
    float hf = (float)h, wf = (float)w;

    float best = INFINITY;
    int bestk = -1;
    for (int i = 0; i < n; ++i) {
        int k = s_cand[i];
        int yck = s_yc[k], xck = s_xc[k];
        if (h >= yck - SS && h < yck + SS && w >= xck - SS && w < xck + SS) {
            float cross = __fadd_rn(__fadd_rn(__fmul_rn(x0v, s_c0[k]), __fmul_rn(x1v, s_c1[k])),
                                    __fmul_rn(x2v, s_c2[k]));
            float t2 = __fsub_rn(__fadd_rn(px2, s_cc[k]), __fmul_rn(2.0f, cross));
            float cd = __fsqrt_rn(fmaxf(t2, 0.0f));
            float dy = __fsub_rn(hf, (float)yck);
            float dx = __fsub_rn(wf, (float)xck);
            float sp = __fsqrt_rn(__fadd_rn(__fmul_rn(dy, dy), __fmul_rn(dx, dx)));
            float d = __fadd_rn(cd, __fmul_rn(MW_OVER_S, sp));
            if (d < best || (d == best && k < bestk)) { best = d; bestk = k; }
        }
    }
    lblf[b * HH * WW + pidx] = (float)bestk;
}

// -------------------------------------------------------------------------
// Assignment (iteration 1): reads updated yc/xc/colors from ws.
// Byte-identical to the round-11-validated kernel (absmax 0.0).
// -------------------------------------------------------------------------
__global__ void k_assign(const float* __restrict__ x,
                         const int* __restrict__ yc,
                         const int* __restrict__ xc,
                         const float* __restrict__ colors,
                         float* __restrict__ lblf) {
    __shared__ int s_yc[NC], s_xc[NC];
    __shared__ float s_c0[NC], s_c1[NC], s_c2[NC], s_cc[NC];
    __shared__ int s_cand[NC];
    __shared__ int s_wc[4];
    int b = blockIdx.z;
    int ty0 = blockIdx.y * 16, tx0 = blockIdx.x * 16;
    int t = threadIdx.y * 16 + threadIdx.x;
    int lane = t & 63, wid = t >> 6;

    bool pred = false;
    if (t < NC) {
        int yck = yc[b * NC + t], xck = xc[b * NC + t];
        s_yc[t] = yck; s_xc[t] = xck;
        float c0 = colors[(b * NC + t) * 3 + 0];
        float c1 = colors[(b * NC + t) * 3 + 1];
        float c2 = colors[(b * NC + t) * 3 + 2];
        s_c0[t] = c0; s_c1[t] = c1; s_c2[t] = c2;
        s_cc[t] = __fadd_rn(__fadd_rn(__fmul_rn(c0, c0), __fmul_rn(c1, c1)), __fmul_rn(c2, c2));
        pred = (yck > ty0 - 17 && yck < ty0 + 32 && xck > tx0 - 17 && xck < tx0 + 32);
    }
    unsigned long long bm = __ballot(pred);
    if (lane == 0) s_wc[wid] = __popcll(bm);
    __syncthreads();
    int base = 0;
    for (int w = 0; w < wid; ++w) base += s_wc[w];
    if (pred) {
        int pos = base + __popcll(bm & ((1ull << lane) - 1ull));
        s_cand[pos] = t;
    }
    int n = s_wc[0] + s_wc[1] + s_wc[2] + s_wc[3];
    __syncthreads();

    int h = ty0 + threadIdx.y, w = tx0 + threadIdx.x;
    const float* xb = x + b * 3 * HH * WW;
    int pidx = h * WW + w;
    float x0v = xb[pidx];
    float x1v = xb[HH * WW + pidx];
    float x2v = xb[2 * HH * WW + pidx];
    float px2 = __fadd_rn(__fadd_rn(__fmul_rn(x0v, x0v), __fmul_rn(x1v, x1v)), __fmul_rn(x2v, x2v));
    float hf = (float)h, wf = (float)w;

    float best = INFINITY;
    int bestk = -1;
    for (int i = 0; i < n; ++i) {
        int k = s_cand[i];
        int yck = s_yc[k], xck = s_xc[k];
        if (h >= yck - SS && h < yck + SS && w >= xck - SS && w < xck + SS) {
            float cross = __fadd_rn(__fadd_rn(__fmul_rn(x0v, s_c0[k]), __fmul_rn(x1v, s_c1[k])),
                                    __fmul_rn(x2v, s_c2[k]));
            float t2 = __fsub_rn(__fadd_rn(px2, s_cc[k]), __fmul_rn(2.0f, cross));
            float cd = __fsqrt_rn(fmaxf(t2, 0.0f));
            float dy = __fsub_rn(hf, (float)yck);
            float dx = __fsub_rn(wf, (float)xck);
            float sp = __fsqrt_rn(__fadd_rn(__fmul_rn(dy, dy), __fmul_rn(dx, dx)));
            float d = __fadd_rn(cd, __fmul_rn(MW_OVER_S, sp));
            if (d < best || (d == best && k < bestk)) { best = d; bestk = k; }
        }
    }
    lblf[b * HH * WW + pidx] = (float)bestk;
}

// -------------------------------------------------------------------------
// Update step: one 256-thread block per (b, k). Order-preserving compaction
// into LDS, then pipelined ordered serial channel sums (same left-fold add
// SEQUENCE as the reference's segment_sum; loads batched as ds_read_b128).
// Byte-identical to the round-11-validated kernel (absmax 0.0).
// -------------------------------------------------------------------------
__global__ void k_update(const float* __restrict__ x,
                         const float* __restrict__ lblf,
                         int* __restrict__ yc, int* __restrict__ xc,
                         float* __restrict__ colors) {
    __shared__ alignas(16) float sc0[1024];
    __shared__ alignas(16) float sc1[1024];
    __shared__ alignas(16) float sc2[1024];
    __shared__ int wsum[4];
    __shared__ int s_isy, s_isx;
    __shared__ float s_fin[3];
    int k = blockIdx.x, b = blockIdx.y;
    int t = threadIdx.x;
    int lane = t & 63, wid = t >> 6;

    int yck = yc[b * NC + k], xck = xc[b * NC + k];
    int y0 = max(0, yck - SS), y1 = min(HH, yck + SS);
    int x0 = max(0, xck - SS), x1 = min(WW, xck + SS);
    int wd = x1 - x0;
    int n = (y1 - y0) * wd;          // <= 1024 = 4 * 256 threads

    const float* xb = x + b * 3 * HH * WW;
    const float* lb = lblf + b * HH * WW;
    float kf = (float)k;

    if (t == 0) { s_isy = 0; s_isx = 0; }
    __syncthreads();

    // pass 1: match mask over this thread's 4 consecutive window-flat indices
    int mask = 0;
    int isy = 0, isx = 0;
    #pragma unroll
    for (int j = 0; j < 4; ++j) {
        int i = 4 * t + j;
        if (i < n) {
            int y = y0 + i / wd, xx = x0 + i % wd;
            if (lb[y * WW + xx] == kf) { mask |= (1 << j); isy += y; isx += xx; }
        }
    }
    int c_t = __popc(mask);

    // wave inclusive scan of per-thread counts
    int inc = c_t;
    for (int off = 1; off < 64; off <<= 1) {
        int u = __shfl_up(inc, off);
        if (lane >= off) inc += u;
    }
    if (lane == 63) wsum[wid] = inc;
    __syncthreads();
    int woff = 0;
    for (int w = 0; w < wid; ++w) woff += wsum[w];
    int pos = woff + inc - c_t;      // exclusive prefix = this thread's write base

    // pass 2: order-preserving compaction of matched colors into LDS
    #pragma unroll
    for (int j = 0; j < 4; ++j) {
        if ((mask >> j) & 1) {
            int i = 4 * t + j;
            int y = y0 + i / wd, xx = x0 + i % wd;
            int idx = y * WW + xx;
            sc0[pos] = xb[idx];
            sc1[pos] = xb[HH * WW + idx];
            sc2[pos] = xb[2 * HH * WW + idx];
            ++pos;
        }
    }
    // integer reductions (exact in any order)
    for (int off = 1; off < 64; off <<= 1) {
        isy += __shfl_xor(isy, off);
        isx += __shfl_xor(isx, off);
    }
    if (lane == 0) { atomicAdd(&s_isy, isy); atomicAdd(&s_isx, isx); }
    __syncthreads();

    int cnt = wsum[0] + wsum[1] + wsum[2] + wsum[3];

    // ordered serial channel sums, pipelined: lanes 0/1/2, one channel each
    if (t < 3) {
        const float* a = (t == 0) ? sc0 : (t == 1) ? sc1 : sc2;
        float s = 0.0f;
        int i = 0;
        for (; i + 8 <= cnt; i += 8) {
            float4 q0 = *(const float4*)(a + i);      // ds_read_b128
            float4 q1 = *(const float4*)(a + i + 4);  // ds_read_b128
            s = __fadd_rn(s, q0.x); s = __fadd_rn(s, q0.y);
            s = __fadd_rn(s, q0.z); s = __fadd_rn(s, q0.w);
            s = __fadd_rn(s, q1.x); s = __fadd_rn(s, q1.y);
            s = __fadd_rn(s, q1.z); s = __fadd_rn(s, q1.w);
        }
        for (; i < cnt; ++i) s = __fadd_rn(s, a[i]);
        s_fin[t] = s;
    }
    __syncthreads();

    if (t == 0 && cnt > 0) {
        float denom = (float)cnt;
        // reference: round(clip(sum/denom, 0, 223)); jnp.round == rint
        float nyf = rintf(fminf(fmaxf(__fdiv_rn((float)s_isy, denom), 0.0f), (float)(HH - 1)));
        float nxf = rintf(fminf(fmaxf(__fdiv_rn((float)s_isx, denom), 0.0f), (float)(WW - 1)));
        yc[b * NC + k] = (int)nyf;
        xc[b * NC + k] = (int)nxf;
        colors[(b * NC + k) * 3 + 0] = __fdiv_rn(s_fin[0], denom);
        colors[(b * NC + k) * 3 + 1] = __fdiv_rn(s_fin[1], denom);
        colors[(b * NC + k) * 3 + 2] = __fdiv_rn(s_fin[2], denom);
    }
}

// -------------------------------------------------------------------------
// Launch sequence (4 dispatches):
//   window_scan -> assign_first(resolve+init_colors+assign) -> update
//   -> assign (final)
// (MAX_ITER=2: only lbl escapes the reference loop, so the 2nd iteration's
//  update is dead and elided.)
// -------------------------------------------------------------------------
extern "C" void kernel_launch(void* const* d_in, const int* in_sizes, int n_in,
                              void* d_out, int out_size, void* d_ws, size_t ws_size,
                              hipStream_t stream) {
    const float* x = (const float*)d_in[0];      // (8,3,224,224) f32
    const float* g = (const float*)d_in[1];      // (8,1,224,224) f32
    float* out = (float*)d_out;
    float* out_cents = out;                      // 8*196*2 floats
    float* lblf = out + BB * NC * 2;             // 8*224*224 floats (labels as f32)

    // workspace layout (all < 64 KB total)
    int* yc = (int*)d_ws;                        // BB*NC
    int* xc = yc + BB * NC;                      // BB*NC
    float* colors = (float*)(xc + BB * NC);      // BB*NC*3
    float* wmin = colors + BB * NC * 3;          // BB*NC
    int* widx = (int*)(wmin + BB * NC);          // BB*NC
    int* wcnt = widx + BB * NC;                  // BB*NC

    dim3 gscan(NC, BB);
    k_window_scan<<<gscan, 64, 0, stream>>>(g, wmin, widx, wcnt);

    dim3 gridA(WW / 16, HH / 16, BB);
    dim3 blkA(16, 16);
    dim3 gupd(NC, BB);
    k_assign_first<<<gridA, blkA, 0, stream>>>(g, x, widx, wcnt, wmin,
                                               yc, xc, colors, out_cents, lblf);
    k_update<<<gupd, 256, 0, stream>>>(x, lblf, yc, xc, colors);     // iter 0 update
    k_assign<<<gridA, blkA, 0, stream>>>(x, yc, xc, colors, lblf);   // iter 1 assign (final)
}